// Round 1
// baseline (1970.681 us; speedup 1.0000x reference)
//
#include <hip/hip_runtime.h>
#include <hip/hip_bf16.h>

// FlashFFN: y = nan_to_num(gelu_tanh(x@W1 + b1) @ W2) + b2
// x [4096,4096] f32, W1 [4096,16384] f32, b1 [16384] f32,
// W2 [16384,4096] f32, b2 [4096] f32, out [4096,4096] f32.
//
// Strategy: bf16 MFMA (16x16x32) m97-style GEMMs; pre-pass casts x->bf16 and
// transpose-casts W1,W2 into B^T (N-major, K-contiguous) bf16 layout so both
// GEMM operands get contiguous-K ds_read_b128 fragments and width-16
// global_load_lds staging.

using bf16 = __hip_bfloat16;
typedef __attribute__((ext_vector_type(4))) float floatx4;
typedef __attribute__((ext_vector_type(8))) short shortx8;

#define TOKENS 4096   // B*S = 2*2048
#define DMODEL 4096
#define DFF    16384

__device__ __forceinline__ void gload_lds16(const void* g, void* l) {
  __builtin_amdgcn_global_load_lds(
      (const __attribute__((address_space(1))) unsigned int*)g,
      (__attribute__((address_space(3))) unsigned int*)l,
      16, 0, 0);
}

__device__ __forceinline__ float gelu_tanh(float x) {
  // JAX default gelu (approximate=True, tanh form)
  float z = 0.7978845608028654f * (x + 0.044715f * x * x * x);
  float e = __expf(2.0f * z);           // overflow->inf gives t=1, underflow->0 gives t=-1: both correct
  float t = 1.0f - 2.0f / (e + 1.0f);
  return 0.5f * x * (1.0f + t);
}

// ---- pre-pass: f32 -> bf16 cast (layout preserved), 8 elems/thread ----
__global__ void cvt_f32_bf16(const float* __restrict__ in, bf16* __restrict__ out) {
  int i = (blockIdx.x * blockDim.x + threadIdx.x) * 8;
  float4 a = *(const float4*)(in + i);
  float4 b = *(const float4*)(in + i + 4);
  union { shortx8 v; bf16 h[8]; } r;
  r.h[0] = __float2bfloat16(a.x); r.h[1] = __float2bfloat16(a.y);
  r.h[2] = __float2bfloat16(a.z); r.h[3] = __float2bfloat16(a.w);
  r.h[4] = __float2bfloat16(b.x); r.h[5] = __float2bfloat16(b.y);
  r.h[6] = __float2bfloat16(b.z); r.h[7] = __float2bfloat16(b.w);
  *(shortx8*)(out + i) = r.v;
}

// ---- pre-pass: transpose + cast. in [R][C] f32 -> out [C][R] bf16 ----
__global__ void transpose_cvt(const float* __restrict__ in, bf16* __restrict__ out,
                              int R, int C) {
  __shared__ float tile[32][33];  // +1 pad: no bank conflicts on transposed read
  int bx = blockIdx.x, by = blockIdx.y;
  int tx = threadIdx.x, ty = threadIdx.y;  // 32 x 8
#pragma unroll
  for (int j = 0; j < 32; j += 8)
    tile[ty + j][tx] = in[(size_t)(by * 32 + ty + j) * C + bx * 32 + tx];
  __syncthreads();
#pragma unroll
  for (int j = 0; j < 32; j += 8)
    out[(size_t)(bx * 32 + ty + j) * R + by * 32 + tx] =
        __float2bfloat16(tile[tx][ty + j]);
}

// ---- m97-style GEMM: C = A @ B with B given transposed (Bt [N][K]) ----
// A [M][K] bf16 row-major, Bt [N][K] bf16 row-major.
// 128x128 block tile, BK=32, 4 waves each computing 64x64 via 4x4 MFMAs.
// FUSE_GELU=1: out bf16 = gelu(acc + bias[col]); FUSE_GELU=0: out f32 =
// nan_guard(acc) + bias[col].
template <int FUSE_GELU>
__global__ void gemm_bt(const bf16* __restrict__ A, const bf16* __restrict__ Bt,
                        const float* __restrict__ bias, void* __restrict__ Cout,
                        int M, int N, int K) {
  __shared__ __align__(16) bf16 As[128 * 32];
  __shared__ __align__(16) bf16 Bs[128 * 32];

  const int tid = threadIdx.x;
  const int wave = tid >> 6;
  const int lane = tid & 63;
  const int m0 = blockIdx.y * 128;
  const int n0 = blockIdx.x * 128;
  const size_t Ks = (size_t)K;

  // staging: wave w covers rows 32w..32w+31 of each tile; one issue = 16 rows
  // (64 lanes x 16B = 1024B = 16 rows x 64B). LDS dest = base + lane*16 which
  // matches [row][k] row-major layout exactly (global_load_lds constraint).
  const bf16* agp = A  + (size_t)(m0 + wave * 32 + (lane >> 2)) * Ks + (lane & 3) * 8;
  const bf16* bgp = Bt + (size_t)(n0 + wave * 32 + (lane >> 2)) * Ks + (lane & 3) * 8;
  bf16* alp = As + wave * 32 * 32;
  bf16* blp = Bs + wave * 32 * 32;

  floatx4 acc[4][4] = {};

  const int wm = (wave & 1) * 64;
  const int wn = (wave >> 1) * 64;
  const int fr = lane & 15;          // A row / B col within 16x16 tile
  const int fq = (lane >> 4) * 8;    // k offset of this lane's 8-elem slice

  for (int k0 = 0; k0 < K; k0 += 32) {
    gload_lds16(agp + k0,           alp);
    gload_lds16(agp + k0 + 16 * Ks, alp + 16 * 32);
    gload_lds16(bgp + k0,           blp);
    gload_lds16(bgp + k0 + 16 * Ks, blp + 16 * 32);
    __syncthreads();   // compiler emits vmcnt(0) drain before barrier

    shortx8 af[4], bfr[4];
#pragma unroll
    for (int i = 0; i < 4; ++i)
      af[i] = *(const shortx8*)(As + (wm + i * 16 + fr) * 32 + fq);
#pragma unroll
    for (int i = 0; i < 4; ++i)
      bfr[i] = *(const shortx8*)(Bs + (wn + i * 16 + fr) * 32 + fq);

#pragma unroll
    for (int mi = 0; mi < 4; ++mi)
#pragma unroll
      for (int ni = 0; ni < 4; ++ni)
        acc[mi][ni] = __builtin_amdgcn_mfma_f32_16x16x32_bf16(
            af[mi], bfr[ni], acc[mi][ni], 0, 0, 0);

    __syncthreads();   // protect LDS from next iteration's staging
  }

  // epilogue. C/D layout (verified m89/m91): col = lane&15, row = (lane>>4)*4 + reg
  const int col0 = n0 + wn + fr;
  const int row0 = m0 + wm + (lane >> 4) * 4;
#pragma unroll
  for (int ni = 0; ni < 4; ++ni) {
    const int col = col0 + ni * 16;
    const float bv = bias[col];
#pragma unroll
    for (int mi = 0; mi < 4; ++mi) {
#pragma unroll
      for (int r = 0; r < 4; ++r) {
        const int row = row0 + mi * 16 + r;
        float v = acc[mi][ni][r];
        if (FUSE_GELU) {
          v = gelu_tanh(v + bv);
          ((bf16*)Cout)[(size_t)row * N + col] = __float2bfloat16(v);
        } else {
          // reference: nan_to_num BEFORE +b2
          if (!isfinite(v)) v = 0.0f;
          ((float*)Cout)[(size_t)row * N + col] = v + bv;
        }
      }
    }
  }
}

extern "C" void kernel_launch(void* const* d_in, const int* in_sizes, int n_in,
                              void* d_out, int out_size, void* d_ws, size_t ws_size,
                              hipStream_t stream) {
  const float* x  = (const float*)d_in[0];
  const float* W1 = (const float*)d_in[1];
  const float* b1 = (const float*)d_in[2];
  const float* W2 = (const float*)d_in[3];
  const float* b2 = (const float*)d_in[4];
  float* out = (float*)d_out;

  // workspace layout (bf16):
  //   xb  [4096 x 4096]   32 MB @ 0
  //   h   [4096 x 16384] 128 MB @ 32 MB
  //   w1t [16384 x 4096] 128 MB @ 160 MB
  //   w2t [4096 x 16384] 128 MB @ 288 MB   (total 416 MB)
  char* ws = (char*)d_ws;
  bf16* xb  = (bf16*)(ws);
  bf16* h   = (bf16*)(ws + (size_t)32  * 1024 * 1024);
  bf16* w1t = (bf16*)(ws + (size_t)160 * 1024 * 1024);
  bf16* w2t = (bf16*)(ws + (size_t)288 * 1024 * 1024);

  // pre-pass
  cvt_f32_bf16<<<(TOKENS * DMODEL / 8) / 256, 256, 0, stream>>>(x, xb);
  transpose_cvt<<<dim3(DFF / 32, DMODEL / 32), dim3(32, 8), 0, stream>>>(W1, w1t, DMODEL, DFF);
  transpose_cvt<<<dim3(DMODEL / 32, DFF / 32), dim3(32, 8), 0, stream>>>(W2, w2t, DFF, DMODEL);

  // GEMM1: h = gelu(x @ W1 + b1)   [4096 x 16384] bf16
  gemm_bt<1><<<dim3(DFF / 128, TOKENS / 128), 256, 0, stream>>>(
      xb, w1t, b1, h, TOKENS, DFF, DMODEL);

  // GEMM2: out = nan_guard(h @ W2) + b2   [4096 x 4096] f32
  gemm_bt<0><<<dim3(DMODEL / 128, TOKENS / 128), 256, 0, stream>>>(
      h, w2t, b2, out, TOKENS, DMODEL, DFF);
}

// Round 2
// 1941.888 us; speedup vs baseline: 1.0148x; 1.0148x over previous
//
#include <hip/hip_runtime.h>
#include <hip/hip_bf16.h>

// FlashFFN: y = nan_to_num(gelu_tanh(x@W1 + b1) @ W2) + b2
// Round 2: (a) XOR-swizzled LDS staging to kill ds_read_b128 bank conflicts
// (applied on the global source address since global_load_lds pins the LDS
// layout to lane order); (b) bandwidth-optimal transpose_cvt (float4 reads,
// shortx8 writes via 64x64 f32 LDS tile).

using bf16 = __hip_bfloat16;
typedef __attribute__((ext_vector_type(4))) float floatx4;
typedef __attribute__((ext_vector_type(8))) short shortx8;

#define TOKENS 4096   // B*S = 2*2048
#define DMODEL 4096
#define DFF    16384

__device__ __forceinline__ void gload_lds16(const void* g, void* l) {
  __builtin_amdgcn_global_load_lds(
      (const __attribute__((address_space(1))) unsigned int*)g,
      (__attribute__((address_space(3))) unsigned int*)l,
      16, 0, 0);
}

__device__ __forceinline__ float gelu_tanh(float x) {
  // JAX default gelu (approximate=True, tanh form)
  float z = 0.7978845608028654f * (x + 0.044715f * x * x * x);
  float e = __expf(2.0f * z);   // inf -> t=1, 0 -> t=-1: both limits correct
  float t = 1.0f - 2.0f / (e + 1.0f);
  return 0.5f * x * (1.0f + t);
}

// ---- pre-pass: f32 -> bf16 cast (layout preserved), 8 elems/thread ----
__global__ void cvt_f32_bf16(const float* __restrict__ in, bf16* __restrict__ out) {
  int i = (blockIdx.x * blockDim.x + threadIdx.x) * 8;
  float4 a = *(const float4*)(in + i);
  float4 b = *(const float4*)(in + i + 4);
  union { shortx8 v; bf16 h[8]; } r;
  r.h[0] = __float2bfloat16(a.x); r.h[1] = __float2bfloat16(a.y);
  r.h[2] = __float2bfloat16(a.z); r.h[3] = __float2bfloat16(a.w);
  r.h[4] = __float2bfloat16(b.x); r.h[5] = __float2bfloat16(b.y);
  r.h[6] = __float2bfloat16(b.z); r.h[7] = __float2bfloat16(b.w);
  *(shortx8*)(out + i) = r.v;
}

// ---- pre-pass: transpose + cast. in [R][C] f32 -> out [C][R] bf16 ----
// 64x64 tile, 256 threads. Read: float4, 4 rows x 16 lanes/row per wave
// (256B contiguous per row). Write: shortx8 (16B) per lane, 8 lanes cover 64
// consecutive output elements (128B contiguous). LDS column gather at pitch
// 65 dwords: banks (rb+j+c)%32 cover each bank exactly 2x per wave -> free.
__global__ void transpose_cvt(const float* __restrict__ in, bf16* __restrict__ out,
                              int R, int C) {
  __shared__ float tile[64][65];
  const int c0 = blockIdx.x * 64, r0 = blockIdx.y * 64;
  const int t = threadIdx.x;
#pragma unroll
  for (int p = 0; p < 4; ++p) {
    int r = p * 16 + (t >> 4);
    int c = (t & 15) * 4;
    float4 v = *(const float4*)(in + (size_t)(r0 + r) * C + c0 + c);
    tile[r][c] = v.x; tile[r][c + 1] = v.y;
    tile[r][c + 2] = v.z; tile[r][c + 3] = v.w;
  }
  __syncthreads();
#pragma unroll
  for (int p = 0; p < 2; ++p) {
    int c = p * 32 + (t >> 3);
    int rb = (t & 7) * 8;
    union { shortx8 v; bf16 h[8]; } u;
#pragma unroll
    for (int j = 0; j < 8; ++j) u.h[j] = __float2bfloat16(tile[rb + j][c]);
    *(shortx8*)(out + (size_t)(c0 + c) * R + r0 + rb) = u.v;
  }
}

// ---- m97-style GEMM with swizzled staging: C = A @ Bt^T ----
// A [M][K] bf16 row-major, Bt [N][K] bf16 row-major.
// 128x128 block tile, BK=32, 4 waves each computing 64x64 via 4x4 MFMAs.
// LDS[row][b] (b = 16B block 0..3) holds global 16B block (row, b ^ ((row>>1)&3)).
// The XOR spreads fragment-read bank_starts over 8 values instead of 2.
template <int FUSE_GELU>
__global__ void gemm_bt(const bf16* __restrict__ A, const bf16* __restrict__ Bt,
                        const float* __restrict__ bias, void* __restrict__ Cout,
                        int M, int N, int K) {
  __shared__ __align__(16) bf16 As[128 * 32];
  __shared__ __align__(16) bf16 Bs[128 * 32];

  const int tid = threadIdx.x;
  const int wave = tid >> 6;
  const int lane = tid & 63;
  const int m0 = blockIdx.y * 128;
  const int n0 = blockIdx.x * 128;
  const size_t Ks = (size_t)K;

  // staging: lane L covers row (L>>2), 16B-block (L&3); source block index is
  // XOR-swizzled: kb_sw = (L&3) ^ s(row), s(row) = (row>>1)&3 = (L>>3)&3.
  // Same s for the +16-row second issue ((16+q)>>1 keeps s mod 4).
  const int srow = lane >> 2;
  const int kbsw = (lane & 3) ^ ((lane >> 3) & 3);
  const bf16* agp = A  + (size_t)(m0 + wave * 32 + srow) * Ks + kbsw * 8;
  const bf16* bgp = Bt + (size_t)(n0 + wave * 32 + srow) * Ks + kbsw * 8;
  bf16* alp = As + wave * 32 * 32;
  bf16* blp = Bs + wave * 32 * 32;

  floatx4 acc[4][4] = {};

  const int wm = (wave & 1) * 64;
  const int wn = (wave >> 1) * 64;
  const int fr = lane & 15;                 // row/col within 16x16 tile
  const int q  = lane >> 4;                 // which 16B k-block (0..3)
  const int sf = (fr >> 1) & 3;             // fragment-read swizzle (=s(row))
  const int fk = ((q ^ sf) * 8);            // swizzled k-element offset

  for (int k0 = 0; k0 < K; k0 += 32) {
    gload_lds16(agp + k0,           alp);
    gload_lds16(agp + k0 + 16 * Ks, alp + 16 * 32);
    gload_lds16(bgp + k0,           blp);
    gload_lds16(bgp + k0 + 16 * Ks, blp + 16 * 32);
    __syncthreads();

    shortx8 af[4], bfr[4];
#pragma unroll
    for (int i = 0; i < 4; ++i)
      af[i] = *(const shortx8*)(As + (wm + i * 16 + fr) * 32 + fk);
#pragma unroll
    for (int i = 0; i < 4; ++i)
      bfr[i] = *(const shortx8*)(Bs + (wn + i * 16 + fr) * 32 + fk);

#pragma unroll
    for (int mi = 0; mi < 4; ++mi)
#pragma unroll
      for (int ni = 0; ni < 4; ++ni)
        acc[mi][ni] = __builtin_amdgcn_mfma_f32_16x16x32_bf16(
            af[mi], bfr[ni], acc[mi][ni], 0, 0, 0);

    __syncthreads();
  }

  // epilogue. C/D layout (m89/m91): col = lane&15, row = (lane>>4)*4 + reg
  const int col0 = n0 + wn + fr;
  const int row0 = m0 + wm + (lane >> 4) * 4;
#pragma unroll
  for (int ni = 0; ni < 4; ++ni) {
    const int col = col0 + ni * 16;
    const float bv = bias[col];
#pragma unroll
    for (int mi = 0; mi < 4; ++mi) {
#pragma unroll
      for (int r = 0; r < 4; ++r) {
        const int row = row0 + mi * 16 + r;
        float v = acc[mi][ni][r];
        if (FUSE_GELU) {
          v = gelu_tanh(v + bv);
          ((bf16*)Cout)[(size_t)row * N + col] = __float2bfloat16(v);
        } else {
          if (!isfinite(v)) v = 0.0f;   // nan_to_num BEFORE +b2
          ((float*)Cout)[(size_t)row * N + col] = v + bv;
        }
      }
    }
  }
}

extern "C" void kernel_launch(void* const* d_in, const int* in_sizes, int n_in,
                              void* d_out, int out_size, void* d_ws, size_t ws_size,
                              hipStream_t stream) {
  const float* x  = (const float*)d_in[0];
  const float* W1 = (const float*)d_in[1];
  const float* b1 = (const float*)d_in[2];
  const float* W2 = (const float*)d_in[3];
  const float* b2 = (const float*)d_in[4];
  float* out = (float*)d_out;

  // workspace layout (bf16): xb 32MB @0, h 128MB @32MB, w1t 128MB @160MB,
  // w2t 128MB @288MB (total 416 MB)
  char* ws = (char*)d_ws;
  bf16* xb  = (bf16*)(ws);
  bf16* h   = (bf16*)(ws + (size_t)32  * 1024 * 1024);
  bf16* w1t = (bf16*)(ws + (size_t)160 * 1024 * 1024);
  bf16* w2t = (bf16*)(ws + (size_t)288 * 1024 * 1024);

  cvt_f32_bf16<<<(TOKENS * DMODEL / 8) / 256, 256, 0, stream>>>(x, xb);
  transpose_cvt<<<dim3(DFF / 64, DMODEL / 64), 256, 0, stream>>>(W1, w1t, DMODEL, DFF);
  transpose_cvt<<<dim3(DMODEL / 64, DFF / 64), 256, 0, stream>>>(W2, w2t, DFF, DMODEL);

  // GEMM1: h = gelu(x @ W1 + b1)   [4096 x 16384] bf16
  gemm_bt<1><<<dim3(DFF / 128, TOKENS / 128), 256, 0, stream>>>(
      xb, w1t, b1, h, TOKENS, DFF, DMODEL);

  // GEMM2: out = nan_guard(h @ W2) + b2   [4096 x 4096] f32
  gemm_bt<0><<<dim3(DMODEL / 128, TOKENS / 128), 256, 0, stream>>>(
      h, w2t, b2, out, TOKENS, DMODEL, DFF);
}